// Round 7
// baseline (687.975 us; speedup 1.0000x reference)
//
#include <hip/hip_runtime.h>
#include <cstdint>
#include <cstddef>

// ---------------------------------------------------------------------------
// Residual VQ (SoundStream Alg.1) on MI355X — R10: spill elimination.
// R9 matched prediction (epilogue diet: 552->448). Remaining signature in
// counters: WRITE_SIZE 96.7 MB vs 34 MB true outputs -> ~63 MB scratch writes
// (+matching reads) = register spills. K-loop live set was acc(128)+r4(64)+
// ring(32)+frags+addr ~ 250-290 > 256 budget -> allocator spills INSIDE the
// K-loop. R10 halves the accumulator: each q runs TWO half-code passes
// (codes 0-511 then 512-1023), acc[2][2]=64 regs -> peak ~180, no spills.
//  - candidate collection per half vs per-half min: provable superset of the
//    true candidate set (half-min >= global min); cap now 4 per 64 codes
//    (stricter than proven 4/128)
//  - B register-ring prefetch flows seamlessly across all 16 (q,half)
//    segments (distance unchanged)
//  - pass1 score-only ladder + ballot id, 8-lane-group pass4, fp64 cnorm,
//    tier-1/tier-2 exactness: verbatim R9 logic re-indexed to 16 slots
// Predicted: WRITE 96.7->~34 MB (spill signature), k_main 448->~330-380.
// ---------------------------------------------------------------------------

#define BATCH 8
#define SEQ   2048
#define DIM   512
#define NUMQ  8
#define CODES 1024
#define NPTS  (BATCH*SEQ)            // 16384
#define MPTS  64                     // points per workgroup
#define NWG   (NPTS/MPTS)            // 256 = 1 WG per CU
#define NTHR  512                    // 8 waves
#define NCHUNK 32                    // K-steps of 16 per quantizer
#define CHUNK_BYTES 32768            // per global chunk: [w':8][g:2][c':128][j:8 f16]

#define OUT_IDX   (BATCH*SEQ*DIM)             // 8388608
#define OUT_LOSS  (OUT_IDX + BATCH*SEQ*NUMQ)  // 8519680

#define WS_LOSS   0                           // 8 doubles
#define WS_CNORM  1024                        // 8192 floats
#define WS_CBH    40960                       // f16 chunk images, 8.39 MB
#define WS_CNORMD (WS_CBH + NUMQ*NCHUNK*CHUNK_BYTES)  // 8192 doubles

typedef _Float16 f16x8  __attribute__((ext_vector_type(8)));
typedef _Float16 f16x4  __attribute__((ext_vector_type(4)));
typedef float    f32x16 __attribute__((ext_vector_type(16)));

__global__ void k_zero(double* loss) {
  if (threadIdx.x < NUMQ) loss[threadIdx.x] = 0.0;
}

// per-code squared norm (fp32; only feeds the approximate scores)
__global__ void k_cnorm(const float* __restrict__ cb, float* __restrict__ cnorm) {
  int r = blockIdx.x * blockDim.x + threadIdx.x;      // 0..8191
  const float* row = cb + (size_t)r * DIM;
  float s = 0.f;
  for (int d = 0; d < DIM; d += 4) {
    float4 v = *(const float4*)(row + d);
    s += v.x * v.x + v.y * v.y + v.z * v.z + v.w * v.w;
  }
  cnorm[r] = s;
}

// per-code squared norm, fp64 (feeds the exact refinement tiers)
__global__ void k_cnormd(const float* __restrict__ cb, double* __restrict__ cnd) {
  int r = blockIdx.x * blockDim.x + threadIdx.x;      // 0..8191
  const float4* row = (const float4*)(cb + (size_t)r * DIM);
  double d0 = 0, d1 = 0, d2 = 0, d3 = 0;
  for (int i = 0; i < 128; i += 4) {
    float4 a = row[i], b = row[i + 1], c = row[i + 2], d = row[i + 3];
    d0 += (double)a.x * a.x + (double)a.y * a.y + (double)a.z * a.z + (double)a.w * a.w;
    d1 += (double)b.x * b.x + (double)b.y * b.y + (double)b.z * b.z + (double)b.w * b.w;
    d2 += (double)c.x * c.x + (double)c.y * c.y + (double)c.z * c.z + (double)c.w * c.w;
    d3 += (double)d.x * d.x + (double)d.y * d.y + (double)d.z * d.z + (double)d.w * d.w;
  }
  cnd[r] = (d0 + d1) + (d2 + d3);
}

// Build f16 codebook chunk images (layout identical to R6-R9):
//   chunk n=(q,ks): byte = w'*4096 + g*2048 + c'*16 + j*2,
//   element = f16(cb[q][w'*128+c'][ks*16+g*8+j])
__global__ void k_prep(const float* __restrict__ cb, unsigned char* __restrict__ cbH) {
  unsigned u = blockIdx.x * blockDim.x + threadIdx.x;   // 0..1048575 (8B units)
  unsigned h  = u & 1;                 // j-half (4 f16)
  unsigned v  = u >> 1;                // 16B granule
  unsigned c  = v & 127;
  unsigned g  = (v >> 7) & 1;
  unsigned w  = (v >> 8) & 7;
  unsigned ks = (v >> 11) & 31;
  unsigned q  = v >> 16;
  unsigned code = (w << 7) | c;
  unsigned k = ks * 16 + g * 8 + h * 4;
  float4 val = *(const float4*)(cb + ((size_t)((q << 10) | code)) * DIM + k);
  f16x4 o;
  o[0] = (_Float16)val.x; o[1] = (_Float16)val.y;
  o[2] = (_Float16)val.z; o[3] = (_Float16)val.w;
  *(f16x4*)(cbH + (size_t)u * 8) = o;
}

// one chunk's 2 B-fragments for this lane (half-code pass: wave owns 64 codes)
struct BF2 { f16x8 b0, b1; };
__device__ __forceinline__ BF2 loadB2(const unsigned char* __restrict__ p) {
  BF2 r;
  r.b0 = *(const f16x8*)(p);
  r.b1 = *(const f16x8*)(p + 512);   // +32 codes
  return r;
}

__launch_bounds__(NTHR, 2)
__global__ void k_main(const float* __restrict__ x, const float* __restrict__ cb,
                       const unsigned char* __restrict__ cbH,
                       const float* __restrict__ cnorm,
                       const double* __restrict__ cnormd,
                       double* __restrict__ lossAcc,
                       float* __restrict__ out)
{
  // A-plane: f16 resid, row m (64) x 512 k; 16B slot s=k/8 stored at
  // slot' = swap3(s) ^ (m&31).
  __shared__ __align__(16) unsigned char Af[MPTS * DIM * 2];    // 64 KB
  __shared__ float          s1w[MPTS][16];      // per (point, half*8+wave) min
  __shared__ unsigned short id1w[MPTS][16];     // local id 0..63
  __shared__ unsigned short cand[MPTS][2][8][4];
  __shared__ unsigned char  ccnt[MPTS][2][8];
  __shared__ float          gmH[MPTS][2];       // per-half global min
  __shared__ unsigned short win2[MPTS][2];      // per-half winner (global code)
  __shared__ unsigned short idxs[MPTS][NUMQ];
  __shared__ double         lred[8];

  const int tid = threadIdx.x;
  const int cl  = tid & 63;
  const int w   = tid >> 6;          // wave 0..7
  const int l31 = cl & 31;
  const int l5  = cl >> 5;           // k-group within wave
  const int wg  = blockIdx.x;

  // residual registers: thread owns point rp = tid>>3, dims rj*64 .. +64
  const int rp = tid >> 3;
  const int rj = tid & 7;
  const size_t gp = (size_t)wg * MPTS + rp;
  float4 r4[16];
  {
    const float4* xr = (const float4*)(x + gp * DIM + rj * 64);
    #pragma unroll
    for (int i = 0; i < 16; ++i) r4[i] = xr[i];
  }

  // per-lane byte base inside a segment's chunk: half h, wave w own codes
  // h*512 + w*64 .. +63 -> image sub-block w' = h*4 + (w>>1), c' base (w&1)*64
  const int laneOff = (l5 << 11) + ((((w & 1) << 6) + l31) << 4);
  const size_t segW = ((size_t)(w >> 1)) << 12;

  // seg base for (q,h): cbH + q<<20 + (h*4 + (w>>1))<<12 + laneOff
  #define SEGBASE(q_, h_) (cbH + ((size_t)(q_) << 20) + (((size_t)(h_) << 14)) + segW + laneOff)

  // prologue: ring holds chunks 0,1 of segment (0,0); hides under A-build
  BF2 s0 = loadB2(SEGBASE(0, 0));
  BF2 s1 = loadB2(SEGBASE(0, 0) + CHUNK_BYTES);

  for (int q = 0; q < NUMQ; ++q) {
    // ---- A-plane build: f16(resid), swizzled (verbatim R6-R9)
    #pragma unroll
    for (int i = 0; i < 8; ++i) {
      float4 a = r4[2 * i], b = r4[2 * i + 1];
      f16x8 v;
      v[0] = (_Float16)a.x; v[1] = (_Float16)a.y; v[2] = (_Float16)a.z; v[3] = (_Float16)a.w;
      v[4] = (_Float16)b.x; v[5] = (_Float16)b.y; v[6] = (_Float16)b.z; v[7] = (_Float16)b.w;
      int sl = ((i << 3) | rj) ^ (rp & 31);            // swap3(j*8+i) ^ row
      *(f16x8*)(Af + rp * 1024 + (sl << 4)) = v;
    }
    __syncthreads();

    #pragma unroll 1
    for (int h = 0; h < 2; ++h) {
      const unsigned char* bh = SEGBASE(q, h);
      const unsigned char* bnext =
          (h == 0) ? SEGBASE(q, 1)
                   : ((q + 1 < NUMQ) ? SEGBASE(q + 1, 0) : nullptr);

      f32x16 acc[2][2];
      #pragma unroll
      for (int mt = 0; mt < 2; ++mt)
        #pragma unroll
        for (int nt = 0; nt < 2; ++nt)
          #pragma unroll
          for (int e = 0; e < 16; ++e) acc[mt][nt][e] = 0.0f;

      // ---- MFMA K-loop: 2-slot register ring, seamless cross-segment
      #pragma unroll 1
      for (int kk = 0; kk < 16; ++kk) {
        const int ks = kk << 1;
        {
          const int s5 = (ks << 1) | l5;
          const int sf = ((((s5 & 7) << 3) | (s5 >> 3)) ^ l31) << 4;
          f16x8 a0 = *(const f16x8*)(Af + l31 * 1024 + sf);
          f16x8 a1 = *(const f16x8*)(Af + 32768 + l31 * 1024 + sf);
          __builtin_amdgcn_s_setprio(1);
          acc[0][0] = __builtin_amdgcn_mfma_f32_32x32x16_f16(a0, s0.b0, acc[0][0], 0, 0, 0);
          acc[0][1] = __builtin_amdgcn_mfma_f32_32x32x16_f16(a0, s0.b1, acc[0][1], 0, 0, 0);
          acc[1][0] = __builtin_amdgcn_mfma_f32_32x32x16_f16(a1, s0.b0, acc[1][0], 0, 0, 0);
          acc[1][1] = __builtin_amdgcn_mfma_f32_32x32x16_f16(a1, s0.b1, acc[1][1], 0, 0, 0);
          __builtin_amdgcn_s_setprio(0);
          const int n2 = ks + 2;
          const unsigned char* pf =
              (n2 < NCHUNK) ? bh + (size_t)n2 * CHUNK_BYTES
                            : (bnext ? bnext + (size_t)(n2 - NCHUNK) * CHUNK_BYTES : nullptr);
          if (pf) s0 = loadB2(pf);
        }
        {
          const int ks1 = ks + 1;
          const int s5 = (ks1 << 1) | l5;
          const int sf = ((((s5 & 7) << 3) | (s5 >> 3)) ^ l31) << 4;
          f16x8 a0 = *(const f16x8*)(Af + l31 * 1024 + sf);
          f16x8 a1 = *(const f16x8*)(Af + 32768 + l31 * 1024 + sf);
          __builtin_amdgcn_s_setprio(1);
          acc[0][0] = __builtin_amdgcn_mfma_f32_32x32x16_f16(a0, s1.b0, acc[0][0], 0, 0, 0);
          acc[0][1] = __builtin_amdgcn_mfma_f32_32x32x16_f16(a0, s1.b1, acc[0][1], 0, 0, 0);
          acc[1][0] = __builtin_amdgcn_mfma_f32_32x32x16_f16(a1, s1.b0, acc[1][0], 0, 0, 0);
          acc[1][1] = __builtin_amdgcn_mfma_f32_32x32x16_f16(a1, s1.b1, acc[1][1], 0, 0, 0);
          __builtin_amdgcn_s_setprio(0);
          const int n3 = ks1 + 2;
          const unsigned char* pf =
              (n3 < NCHUNK) ? bh + (size_t)n3 * CHUNK_BYTES
                            : (bnext ? bnext + (size_t)(n3 - NCHUNK) * CHUNK_BYTES : nullptr);
          if (pf) s1 = loadB2(pf);
        }
      }

      // ---- scores = -2*dot + ||c||^2 (approximate; f16-rounded inputs)
      {
        const float* cnq = cnorm + (q << 10) + (h << 9) + (w << 6) + l31;
        const float cn0 = cnq[0], cn1 = cnq[32];
        #pragma unroll
        for (int mt = 0; mt < 2; ++mt) {
          acc[mt][0] = acc[mt][0] * -2.0f + cn0;
          acc[mt][1] = acc[mt][1] * -2.0f + cn1;
        }
      }

      // ---- pass 1: per-wave per-point top-1 over this wave-half's 64 codes
      // C/D layout 32x32: col = lane&31, row = (r&3)+8*(r>>2)+4*(lane>>5)
      const int hw = (h << 3) | w;
      #pragma unroll
      for (int mt = 0; mt < 2; ++mt)
        #pragma unroll
        for (int r = 0; r < 16; ++r) {
          float s = acc[mt][0][r]; int bi = l31;
          if (acc[mt][1][r] < s) { s = acc[mt][1][r]; bi = 32 + l31; }
          float smin = s;
          #pragma unroll
          for (int m = 1; m < 32; m <<= 1) smin = fminf(smin, __shfl_xor(smin, m));
          unsigned long long bm = __ballot(s == smin);
          unsigned half = l5 ? (unsigned)(bm >> 32) : (unsigned)bm;
          int first = __builtin_ctz(half) + (l5 << 5);
          int id = __shfl(bi, first);
          if (l31 == 0) {
            int p = mt * 32 + (r & 3) + 8 * (r >> 2) + 4 * l5;
            s1w[p][hw] = smin; id1w[p][hw] = (unsigned short)id;
          }
        }
      __syncthreads();

      // ---- pass 2h: per-half global min + provisional winner
      if (tid < MPTS) {
        int p = tid;
        float bs = s1w[p][(h << 3)]; int bw = 0;
        #pragma unroll
        for (int ww = 1; ww < 8; ++ww) {
          float s = s1w[p][(h << 3) | ww];
          if (s < bs) { bs = s; bw = ww; }
        }
        gmH[p][h] = bs;
        win2[p][h] = (unsigned short)((h << 9) + (bw << 6) + id1w[p][(h << 3) | bw]);
      }
      __syncthreads();

      // ---- pass 3: ballot candidates within margin of PER-HALF min
      //      (superset of true candidate set: half-min >= global min)
      #pragma unroll
      for (int mt = 0; mt < 2; ++mt)
        #pragma unroll
        for (int r = 0; r < 16; ++r) {
          const int p0 = mt * 32 + (r & 3) + 8 * (r >> 2);
          const float g0 = gmH[p0][h], g1 = gmH[p0 + 4][h];
          const float lim0 = g0 + 1.5f + 1e-4f * fabsf(g0);
          const float lim1 = g1 + 1.5f + 1e-4f * fabsf(g1);
          const float lim = l5 ? lim1 : lim0;
          unsigned long long b0 = __ballot(acc[mt][0][r] <= lim);
          unsigned long long b1 = __ballot(acc[mt][1][r] <= lim);
          if (cl == 0 || cl == 32) {
            const int p = p0 + (cl >> 3);
            unsigned short* cd = &cand[p][h][w][0];
            unsigned m0 = (cl == 0) ? (unsigned)b0 : (unsigned)(b0 >> 32);
            unsigned m1 = (cl == 0) ? (unsigned)b1 : (unsigned)(b1 >> 32);
            int n = 0;
            while (m0 && n < 4) { int bt = __builtin_ctz(m0); m0 &= m0 - 1; cd[n++] = (unsigned short)bt; }
            while (m1 && n < 4) { int bt = __builtin_ctz(m1); m1 &= m1 - 1; cd[n++] = (unsigned short)(32 + bt); }
            ccnt[p][h][w] = (unsigned char)n;
          }
        }
      __syncthreads();
    } // h

    // ---- pass 4: refinement tiers, 8-lane-group parallel (R9 logic,
    //      16 candidate slots). Group g of wave w refines point p=w*8+g.
    {
      const int g  = cl >> 3;
      const int gl = cl & 7;
      const int p  = (w << 3) + g;          // == rp
      int tot = 0;
      #pragma unroll
      for (int s = 0; s < 16; ++s) tot += ccnt[p][s >> 3][s & 7];
      int winner;
      {
        float g0 = gmH[p][0], g1 = gmH[p][1];
        winner = (g0 <= g1) ? win2[p][0] : win2[p][1];
      }
      int mtot = tot;
      #pragma unroll
      for (int m = 1; m < 64; m <<= 1) { int o = __shfl_xor(mtot, m); if (o > mtot) mtot = o; }
      if (mtot > 1) {
        double bs = 1.0e300, bs2 = 1.0e300; int bi = 0x7FFFFFFF;
        #pragma unroll 1
        for (int k = 0; k < mtot; ++k) {
          int cc = -1;
          if (tot > 1 && k < tot) {
            int rem = k, slot = 0;
            #pragma unroll 1
            for (; slot < 15; ++slot) {
              int nn = ccnt[p][slot >> 3][slot & 7];
              if (rem < nn) break; rem -= nn;
            }
            cc = ((slot >> 3) << 9) + ((slot & 7) << 6) + cand[p][slot >> 3][slot & 7][rem];
          }
          double dt = 0.0;
          if (cc >= 0) {
            // tier 1: fp64 dot vs exact fp32 residual (in regs), 4-way ILP
            const float4* cr = (const float4*)(cb + ((size_t)q * CODES + cc) * DIM + gl * 64);
            double d0 = 0, d1 = 0, d2 = 0, d3 = 0;
            #pragma unroll
            for (int i = 0; i < 16; i += 4) {
              float4 c0 = cr[i], c1 = cr[i + 1], c2 = cr[i + 2], c3 = cr[i + 3];
              d0 += (double)r4[i].x * c0.x + (double)r4[i].y * c0.y
                  + (double)r4[i].z * c0.z + (double)r4[i].w * c0.w;
              d1 += (double)r4[i + 1].x * c1.x + (double)r4[i + 1].y * c1.y
                  + (double)r4[i + 1].z * c1.z + (double)r4[i + 1].w * c1.w;
              d2 += (double)r4[i + 2].x * c2.x + (double)r4[i + 2].y * c2.y
                  + (double)r4[i + 2].z * c2.z + (double)r4[i + 2].w * c2.w;
              d3 += (double)r4[i + 3].x * c3.x + (double)r4[i + 3].y * c3.y
                  + (double)r4[i + 3].z * c3.z + (double)r4[i + 3].w * c3.w;
            }
            dt = (d0 + d1) + (d2 + d3);
          }
          #pragma unroll
          for (int m = 1; m < 8; m <<= 1) dt += __shfl_xor(dt, m);
          if (cc >= 0) {
            double s = -2.0 * dt + cnormd[(q << 10) + cc];
            if (s < bs) { bs2 = bs; bs = s; bi = cc; }
            else if (s < bs2) { bs2 = s; }
          }
        }
        // tier 2: exact fp64 chain rebuild from x (rare: <1e-3 gap)
        if (tot > 1 && bs2 - bs <= 1e-3 + 1e-6 * fabs(bs)) {
          bs = 1.0e300; bi = 0x7FFFFFFF;
          const float4* xr2 = (const float4*)(x + gp * DIM + gl * 64);
          #pragma unroll 1
          for (int k = 0; k < tot; ++k) {
            int rem = k, slot = 0;
            #pragma unroll 1
            for (; slot < 15; ++slot) {
              int nn = ccnt[p][slot >> 3][slot & 7];
              if (rem < nn) break; rem -= nn;
            }
            const int cc = ((slot >> 3) << 9) + ((slot & 7) << 6) + cand[p][slot >> 3][slot & 7][rem];
            const float4* cr = (const float4*)(cb + ((size_t)q * CODES + cc) * DIM + gl * 64);
            double dt = 0.0;
            #pragma unroll 1
            for (int i = 0; i < 16; ++i) {
              float4 xv = xr2[i];
              double rhx = xv.x, rhy = xv.y, rhz = xv.z, rhw = xv.w;
              #pragma unroll 1
              for (int t2 = 0; t2 < q; ++t2) {
                const float4* qr = (const float4*)(cb + ((size_t)t2 * CODES + idxs[p][t2]) * DIM + gl * 64);
                float4 qv = qr[i];
                rhx -= (double)qv.x; rhy -= (double)qv.y;
                rhz -= (double)qv.z; rhw -= (double)qv.w;
              }
              float4 cv = cr[i];
              dt += rhx * cv.x + rhy * cv.y + rhz * cv.z + rhw * cv.w;
            }
            #pragma unroll
            for (int m = 1; m < 8; m <<= 1) dt += __shfl_xor(dt, m);
            double s = -2.0 * dt + cnormd[(q << 10) + cc];
            if (s < bs || (s == bs && cc < bi)) { bs = s; bi = cc; }
          }
        }
        if (tot > 1) winner = bi;
      }
      if (gl == 0) idxs[p][q] = (unsigned short)winner;
    }
    __syncthreads();

    // ---- pass 5: residual update (exact fp32 chain) + commit loss (fp64,
    //      2-way ILP partials)
    {
      const int win = idxs[rp][q];
      const float4* cr = (const float4*)(cb + ((size_t)q * CODES + win) * DIM + rj * 64);
      double ls0 = 0.0, ls1 = 0.0;
      #pragma unroll
      for (int i = 0; i < 16; i += 2) {
        float4 c0 = cr[i], c1 = cr[i + 1];
        float dx0 = c0.x - r4[i].x, dy0 = c0.y - r4[i].y;
        float dz0 = c0.z - r4[i].z, dw0 = c0.w - r4[i].w;
        ls0 += (double)dx0 * dx0 + (double)dy0 * dy0 + (double)dz0 * dz0 + (double)dw0 * dw0;
        r4[i].x -= c0.x; r4[i].y -= c0.y; r4[i].z -= c0.z; r4[i].w -= c0.w;
        float dx1 = c1.x - r4[i + 1].x, dy1 = c1.y - r4[i + 1].y;
        float dz1 = c1.z - r4[i + 1].z, dw1 = c1.w - r4[i + 1].w;
        ls1 += (double)dx1 * dx1 + (double)dy1 * dy1 + (double)dz1 * dz1 + (double)dw1 * dw1;
        r4[i + 1].x -= c1.x; r4[i + 1].y -= c1.y; r4[i + 1].z -= c1.z; r4[i + 1].w -= c1.w;
      }
      double ls = ls0 + ls1;
      #pragma unroll
      for (int m = 1; m < 64; m <<= 1) ls += __shfl_xor(ls, m);
      if (cl == 0) lred[w] = ls;
      __syncthreads();
      if (tid == 0) {
        double t = lred[0] + lred[1] + lred[2] + lred[3]
                 + lred[4] + lred[5] + lred[6] + lred[7];
        atomicAdd(lossAcc + q, t);
      }
      __syncthreads();
    }
  } // q

  // ---- outputs: quantized = x - resid_final; indices as float
  {
    const float4* xr = (const float4*)(x + gp * DIM + rj * 64);
    float4* orow = (float4*)(out + gp * DIM + rj * 64);
    #pragma unroll
    for (int i = 0; i < 16; ++i) {
      float4 xv = xr[i];
      float4 o;
      o.x = xv.x - r4[i].x; o.y = xv.y - r4[i].y;
      o.z = xv.z - r4[i].z; o.w = xv.w - r4[i].w;
      orow[i] = o;
    }
  }
  if (tid < MPTS) {
    float* ob = out + OUT_IDX + ((size_t)wg * MPTS + tid) * NUMQ;
    #pragma unroll
    for (int j = 0; j < NUMQ; ++j) ob[j] = (float)idxs[tid][j];
  }
}

__global__ void k_fin(const double* __restrict__ loss, float* __restrict__ out) {
  int t = threadIdx.x;
  if (t < NUMQ)
    out[OUT_LOSS + t] = (float)(loss[t] / (double)((size_t)BATCH * SEQ * DIM));
}

extern "C" void kernel_launch(void* const* d_in, const int* in_sizes, int n_in,
                              void* d_out, int out_size, void* d_ws, size_t ws_size,
                              hipStream_t stream) {
  (void)in_sizes; (void)n_in; (void)out_size; (void)ws_size;
  const float* x  = (const float*)d_in[0];
  const float* cb = (const float*)d_in[1];
  float* out = (float*)d_out;
  char* ws = (char*)d_ws;
  double* loss = (double*)(ws + WS_LOSS);
  float* cnorm = (float*)(ws + WS_CNORM);
  unsigned char* cbH = (unsigned char*)(ws + WS_CBH);   // 8.39 MB
  double* cnormd = (double*)(ws + WS_CNORMD);           // 64 KB

  k_zero<<<1, 64, 0, stream>>>(loss);
  k_cnorm<<<NUMQ * CODES / 256, 256, 0, stream>>>(cb, cnorm);
  k_cnormd<<<NUMQ * CODES / 256, 256, 0, stream>>>(cb, cnormd);
  k_prep<<<NUMQ * NCHUNK * CHUNK_BYTES / 8 / 256, 256, 0, stream>>>(cb, cbH);
  k_main<<<NWG, NTHR, 0, stream>>>(x, cb, cbH, cnorm, cnormd, loss, out);
  k_fin<<<1, 64, 0, stream>>>(loss, out);
}